// Round 3
// baseline (522.823 us; speedup 1.0000x reference)
//
#include <hip/hip_runtime.h>
#include <hip/hip_bf16.h>
#include <stdint.h>

// Problem constants (B=4, T=1024, D=1024, E=8, HD=4096)
#define NE 8
#define DIM 1024
#define HDIM 4096
#define NTOK 4096
#define KSPLIT 4
#define MAXT 40   // max occupied 128-row m-tiles: 32 full + 8 partial

typedef unsigned short ushort_t;
typedef __attribute__((ext_vector_type(4))) float f32x4;
typedef __attribute__((ext_vector_type(8))) short bf16x8;

// RNE float -> bf16 bits
__device__ __forceinline__ ushort_t f2b(float f) {
  union { float f; unsigned u; } c; c.f = f;
  unsigned u = c.u;
  return (ushort_t)((u + 0x7fffu + ((u >> 16) & 1u)) >> 16);
}

// async global->LDS, 16 bytes per lane; LDS dest = wave-uniform base + lane*16
__device__ __forceinline__ void gl2lds16(const void* g, void* l) {
  __builtin_amdgcn_global_load_lds(
      (__attribute__((address_space(1))) void*)g,
      (__attribute__((address_space(3))) void*)l, 16, 0, 0);
}

// ---------------- router: logits fp32 + argmax + count (fused) --------------
__global__ __launch_bounds__(256) void router_kernel(
    const float* __restrict__ x, const float* __restrict__ rw,
    int* __restrict__ eid, int* __restrict__ rank, int* __restrict__ cnt) {
  __shared__ float w[NE * 1028];  // stride 1028 to spread LDS banks
  for (int i = threadIdx.x; i < NE * DIM; i += 256) {
    int e = i >> 10, d = i & 1023;
    w[e * 1028 + d] = rw[i];
  }
  __syncthreads();
  int grp = threadIdx.x >> 3;   // 32 tokens / block
  int e = threadIdx.x & 7;      // one expert per lane-in-group
  int t = blockIdx.x * 32 + grp;
  const float4* xr = (const float4*)(x + (size_t)t * DIM);
  const float4* wr = (const float4*)(w + e * 1028);
  float acc = 0.f;
#pragma unroll 4
  for (int i = 0; i < DIM / 4; ++i) {
    float4 xv = xr[i], wv = wr[i];
    acc += xv.x * wv.x + xv.y * wv.y + xv.z * wv.z + xv.w * wv.w;
  }
  float v = acc; int ie = e;
#pragma unroll
  for (int m = 4; m; m >>= 1) {
    float ov = __shfl_xor(v, m, 8);
    int oi = __shfl_xor(ie, m, 8);
    if (ov > v || (ov == v && oi < ie)) { v = ov; ie = oi; }
  }
  if (e == 0) {
    eid[t] = ie;
    rank[t] = atomicAdd(&cnt[ie], 1);
  }
}

// prefix-sum + build dense m-tile table (expert id, row offset within expert)
__global__ void scan_kernel(const int* __restrict__ cnt, int* __restrict__ offs,
                            int* __restrict__ tile_e, int* __restrict__ tile_m,
                            int* __restrict__ ntiles) {
  if (threadIdx.x == 0) {
    int s = 0, nt = 0;
    for (int e = 0; e < NE; ++e) {
      offs[e] = s;
      int c = cnt[e];
      for (int m = 0; m < c; m += 128) { tile_e[nt] = e; tile_m[nt] = m; ++nt; }
      s += c;
    }
    offs[NE] = s;
    *ntiles = nt;
  }
}

// one block per token: write sorted[] and gather x row -> bf16 grouped matrix
__global__ __launch_bounds__(256) void gather_kernel(
    const float* __restrict__ x, const int* __restrict__ eid,
    const int* __restrict__ rank, const int* __restrict__ offs,
    int* __restrict__ sorted, ushort_t* __restrict__ Xg) {
  int t = blockIdx.x;
  int e = eid[t];
  int pos = offs[e] + rank[t];
  if (threadIdx.x == 0) sorted[pos] = t;
  int i = threadIdx.x;  // 256 threads, 4 floats each
  float4 v = ((const float4*)(x + (size_t)t * DIM))[i];
  ushort4 o = make_ushort4(f2b(v.x), f2b(v.y), f2b(v.z), f2b(v.w));
  *(ushort4*)(Xg + (size_t)pos * DIM + i * 4) = o;
}

// ---------------- weight conversion ----------------------------------------
// fc[e][d][h] fp32 -> fct[e][h][d] bf16 (transpose so GEMM1 B is B^T-form)
__global__ __launch_bounds__(256) void transpose_fc_kernel(
    const float* __restrict__ fc, ushort_t* __restrict__ fct) {
  __shared__ float tile[32][33];
  int e = blockIdx.z;
  int h0 = blockIdx.x * 32, d0 = blockIdx.y * 32;
  int c = threadIdx.x & 31, r0 = threadIdx.x >> 5;
  const float* src = fc + ((size_t)e * DIM + d0) * HDIM + h0 + c;
#pragma unroll
  for (int i = 0; i < 4; ++i) {
    int r = r0 + i * 8;
    tile[r][c] = src[(size_t)r * HDIM];
  }
  __syncthreads();
  ushort_t* dst = fct + ((size_t)e * HDIM + h0) * DIM + d0 + c;
#pragma unroll
  for (int i = 0; i < 4; ++i) {
    int r = r0 + i * 8;
    dst[(size_t)r * DIM] = f2b(tile[c][r]);
  }
}

// proj fp32 -> bf16 elementwise (proj [D][HD] is already B^T-form for GEMM2)
__global__ __launch_bounds__(256) void convert_kernel(
    const float* __restrict__ p, ushort_t* __restrict__ o) {
  size_t i = (size_t)blockIdx.x * 256 + threadIdx.x;
  float4 v = ((const float4*)p)[i];
  ushort4 u = make_ushort4(f2b(v.x), f2b(v.y), f2b(v.z), f2b(v.w));
  ((ushort4*)o)[i] = u;
}

// ---------------- GEMM1: H = relu(Xg @ fct^T)^2, bf16 out -------------------
// C-tile 128x128, 4 waves (2x2), each wave 64x64 = 4x4 of 16x16x32 MFMA
// grid: (HDIM/128, MAXT) with dense tile table
__global__ __launch_bounds__(256, 2) void gemm1_kernel(
    const ushort_t* __restrict__ Xg, const ushort_t* __restrict__ fct,
    const int* __restrict__ offs, const int* __restrict__ tile_e,
    const int* __restrict__ tile_m, const int* __restrict__ ntiles,
    ushort_t* __restrict__ H) {
  if ((int)blockIdx.y >= *ntiles) return;
  int e = tile_e[blockIdx.y];
  int mb = tile_m[blockIdx.y];   // row offset within expert
  int m0 = offs[e];
  int Me = offs[e + 1] - m0;
  int n0 = blockIdx.x * 128;

  __shared__ ushort_t As[128 * 32];
  __shared__ ushort_t Bs[128 * 32];

  int tid = threadIdx.x;
  int wave = tid >> 6;
  int lane = tid & 63;

  const ushort_t* ap[2]; const ushort_t* bp[2];
  ushort_t* al[2]; ushort_t* bl[2];
#pragma unroll
  for (int q = 0; q < 2; ++q) {
    int rl = (wave * 2 + q) * 16 + (lane >> 2);
    int kc = (lane & 3) * 8;
    int rg = mb + rl; if (rg >= Me) rg = Me - 1;  // clamp tail rows
    ap[q] = Xg + (size_t)(m0 + rg) * DIM + kc;
    bp[q] = fct + ((size_t)e * HDIM + n0 + rl) * DIM + kc;
    al[q] = &As[(wave * 2 + q) * 512];
    bl[q] = &Bs[(wave * 2 + q) * 512];
  }

  f32x4 acc[4][4] = {};
  int wm = (wave & 1) * 64;
  int wn = (wave >> 1) * 64;
  int fr = lane & 15;
  int kq = (lane >> 4) * 8;

  for (int k0 = 0; k0 < DIM; k0 += 32) {
    gl2lds16(ap[0] + k0, al[0]);
    gl2lds16(ap[1] + k0, al[1]);
    gl2lds16(bp[0] + k0, bl[0]);
    gl2lds16(bp[1] + k0, bl[1]);
    __syncthreads();  // drains vmcnt(0) then barrier
    bf16x8 af[4], bf[4];
#pragma unroll
    for (int i = 0; i < 4; ++i) {
      af[i] = *(const bf16x8*)&As[(wm + i * 16 + fr) * 32 + kq];
      bf[i] = *(const bf16x8*)&Bs[(wn + i * 16 + fr) * 32 + kq];
    }
#pragma unroll
    for (int i = 0; i < 4; ++i)
#pragma unroll
      for (int j = 0; j < 4; ++j)
        acc[i][j] = __builtin_amdgcn_mfma_f32_16x16x32_bf16(af[i], bf[j], acc[i][j], 0, 0, 0);
    __syncthreads();
  }

  int cq = (lane >> 4) * 4;
#pragma unroll
  for (int i = 0; i < 4; ++i) {
#pragma unroll
    for (int r = 0; r < 4; ++r) {
      int rl = wm + i * 16 + cq + r;
      int rg = mb + rl;
      if (rg < Me) {
        ushort_t* dst = H + (size_t)(m0 + rg) * HDIM + n0 + wn + (lane & 15);
#pragma unroll
        for (int j = 0; j < 4; ++j) {
          float v = acc[i][j][r];
          v = fmaxf(v, 0.f);
          dst[j * 16] = f2b(v * v);
        }
      }
    }
  }
}

// ---------------- GEMM2: out[token] += H @ proj^T, split-K + fp32 atomics ---
// grid: (DIM/128, MAXT, KSPLIT) with dense tile table
__global__ __launch_bounds__(256, 2) void gemm2_kernel(
    const ushort_t* __restrict__ Hm, const ushort_t* __restrict__ pjb,
    const int* __restrict__ offs, const int* __restrict__ tile_e,
    const int* __restrict__ tile_m, const int* __restrict__ ntiles,
    const int* __restrict__ sorted, float* __restrict__ out) {
  if ((int)blockIdx.y >= *ntiles) return;
  int e = tile_e[blockIdx.y];
  int mb = tile_m[blockIdx.y];
  int ks = blockIdx.z;
  int m0 = offs[e];
  int Me = offs[e + 1] - m0;
  int n0 = blockIdx.x * 128;

  __shared__ ushort_t As[128 * 32];
  __shared__ ushort_t Bs[128 * 32];

  int tid = threadIdx.x;
  int wave = tid >> 6;
  int lane = tid & 63;

  const ushort_t* ap[2]; const ushort_t* bp[2];
  ushort_t* al[2]; ushort_t* bl[2];
#pragma unroll
  for (int q = 0; q < 2; ++q) {
    int rl = (wave * 2 + q) * 16 + (lane >> 2);
    int kc = (lane & 3) * 8;
    int rg = mb + rl; if (rg >= Me) rg = Me - 1;
    ap[q] = Hm + (size_t)(m0 + rg) * HDIM + kc;
    bp[q] = pjb + ((size_t)e * DIM + n0 + rl) * HDIM + kc;
    al[q] = &As[(wave * 2 + q) * 512];
    bl[q] = &Bs[(wave * 2 + q) * 512];
  }

  f32x4 acc[4][4] = {};
  int wm = (wave & 1) * 64;
  int wn = (wave >> 1) * 64;
  int fr = lane & 15;
  int kq = (lane >> 4) * 8;

  int kbeg = ks * (HDIM / KSPLIT);
  int kend = kbeg + (HDIM / KSPLIT);
  for (int k0 = kbeg; k0 < kend; k0 += 32) {
    gl2lds16(ap[0] + k0, al[0]);
    gl2lds16(ap[1] + k0, al[1]);
    gl2lds16(bp[0] + k0, bl[0]);
    gl2lds16(bp[1] + k0, bl[1]);
    __syncthreads();
    bf16x8 af[4], bf[4];
#pragma unroll
    for (int i = 0; i < 4; ++i) {
      af[i] = *(const bf16x8*)&As[(wm + i * 16 + fr) * 32 + kq];
      bf[i] = *(const bf16x8*)&Bs[(wn + i * 16 + fr) * 32 + kq];
    }
#pragma unroll
    for (int i = 0; i < 4; ++i)
#pragma unroll
      for (int j = 0; j < 4; ++j)
        acc[i][j] = __builtin_amdgcn_mfma_f32_16x16x32_bf16(af[i], bf[j], acc[i][j], 0, 0, 0);
    __syncthreads();
  }

  int cq = (lane >> 4) * 4;
#pragma unroll
  for (int i = 0; i < 4; ++i) {
#pragma unroll
    for (int r = 0; r < 4; ++r) {
      int rl = wm + i * 16 + cq + r;
      int rg = mb + rl;
      if (rg < Me) {
        int tok = sorted[m0 + rg];
        float* dst = out + (size_t)tok * DIM + n0 + wn + (lane & 15);
#pragma unroll
        for (int j = 0; j < 4; ++j) atomicAdd(dst + j * 16, acc[i][j][r]);
      }
    }
  }
}

// ---------------- launch -----------------------------------------------------
extern "C" void kernel_launch(void* const* d_in, const int* in_sizes, int n_in,
                              void* d_out, int out_size, void* d_ws, size_t ws_size,
                              hipStream_t stream) {
  const float* x  = (const float*)d_in[0];
  const float* rw = (const float*)d_in[1];
  const float* fc = (const float*)d_in[2];
  const float* pj = (const float*)d_in[3];
  float* out = (float*)d_out;
  char* ws = (char*)d_ws;

  // workspace layout (needs ~104 MB)
  int* eid        = (int*)(ws + 0x0000);       // 16KB
  int* rank       = (int*)(ws + 0x4000);       // 16KB
  int* cnt        = (int*)(ws + 0x8000);       // 32B
  int* offs       = (int*)(ws + 0x8100);       // 36B
  int* tile_e     = (int*)(ws + 0x8200);       // 160B
  int* tile_m     = (int*)(ws + 0x8600);       // 160B
  int* ntiles     = (int*)(ws + 0x8a00);       // 4B
  int* sorted     = (int*)(ws + 0x9000);       // 16KB
  ushort_t* Xg    = (ushort_t*)(ws + 0x10000);    // 8MB  [4096][1024] bf16
  ushort_t* H     = (ushort_t*)(ws + 0x810000);   // 32MB [4096][4096] bf16
  ushort_t* W     = (ushort_t*)(ws + 0x2810000);  // 64MB fct, then reused for proj bf16

  hipMemsetAsync(cnt, 0, 32, stream);
  hipMemsetAsync(out, 0, (size_t)out_size * sizeof(float), stream);
  router_kernel<<<NTOK / 32, 256, 0, stream>>>(x, rw, eid, rank, cnt);
  scan_kernel<<<1, 64, 0, stream>>>(cnt, offs, tile_e, tile_m, ntiles);
  gather_kernel<<<NTOK, 256, 0, stream>>>(x, eid, rank, offs, sorted, Xg);
  transpose_fc_kernel<<<dim3(HDIM / 32, DIM / 32, NE), 256, 0, stream>>>(fc, W);
  gemm1_kernel<<<dim3(HDIM / 128, MAXT), 256, 0, stream>>>(Xg, W, offs, tile_e, tile_m, ntiles, H);
  convert_kernel<<<(NE * DIM * HDIM / 4) / 256, 256, 0, stream>>>(pj, W);
  gemm2_kernel<<<dim3(DIM / 128, MAXT, KSPLIT), 256, 0, stream>>>(H, W, offs, tile_e, tile_m, ntiles, sorted, out);
}

// Round 4
// 492.204 us; speedup vs baseline: 1.0622x; 1.0622x over previous
//
#include <hip/hip_runtime.h>
#include <hip/hip_bf16.h>
#include <stdint.h>

// Problem constants (B=4, T=1024, D=1024, E=8, HD=4096)
#define NE 8
#define DIM 1024
#define HDIM 4096
#define NTOK 4096
#define KSPLIT 4
#define MAXT 40   // max occupied 128-row m-tiles: 32 full + 8 partial

typedef unsigned short ushort_t;
typedef __attribute__((ext_vector_type(4))) float f32x4;
typedef __attribute__((ext_vector_type(8))) short bf16x8;

// RNE float -> bf16 bits
__device__ __forceinline__ ushort_t f2b(float f) {
  union { float f; unsigned u; } c; c.f = f;
  unsigned u = c.u;
  return (ushort_t)((u + 0x7fffu + ((u >> 16) & 1u)) >> 16);
}

// truncate-pack 8 fp32 (LDS) -> bf16x8 via v_perm (1 instr / 2 elems)
__device__ __forceinline__ bf16x8 cvt8(const float* p) {
  f32x4 lo = *(const f32x4*)p;
  f32x4 hi = *(const f32x4*)(p + 4);
  union { unsigned u[4]; bf16x8 v; } r;
  union { float f; unsigned u; } a, b;
  a.f = lo[0]; b.f = lo[1]; r.u[0] = __builtin_amdgcn_perm(b.u, a.u, 0x07060302);
  a.f = lo[2]; b.f = lo[3]; r.u[1] = __builtin_amdgcn_perm(b.u, a.u, 0x07060302);
  a.f = hi[0]; b.f = hi[1]; r.u[2] = __builtin_amdgcn_perm(b.u, a.u, 0x07060302);
  a.f = hi[2]; b.f = hi[3]; r.u[3] = __builtin_amdgcn_perm(b.u, a.u, 0x07060302);
  return r.v;
}

// async global->LDS, 16 bytes per lane; LDS dest = wave-uniform base + lane*16
__device__ __forceinline__ void gl2lds16(const void* g, void* l) {
  __builtin_amdgcn_global_load_lds(
      (__attribute__((address_space(1))) void*)g,
      (__attribute__((address_space(3))) void*)l, 16, 0, 0);
}

// ---------------- router: logits fp32 + argmax + count (fused) --------------
__global__ __launch_bounds__(256) void router_kernel(
    const float* __restrict__ x, const float* __restrict__ rw,
    int* __restrict__ eid, int* __restrict__ rank, int* __restrict__ cnt) {
  __shared__ float w[NE * 1028];  // stride 1028 to spread LDS banks
  for (int i = threadIdx.x; i < NE * DIM; i += 256) {
    int e = i >> 10, d = i & 1023;
    w[e * 1028 + d] = rw[i];
  }
  __syncthreads();
  int grp = threadIdx.x >> 3;   // 32 tokens / block
  int e = threadIdx.x & 7;      // one expert per lane-in-group
  int t = blockIdx.x * 32 + grp;
  const float4* xr = (const float4*)(x + (size_t)t * DIM);
  const float4* wr = (const float4*)(w + e * 1028);
  float acc = 0.f;
#pragma unroll 4
  for (int i = 0; i < DIM / 4; ++i) {
    float4 xv = xr[i], wv = wr[i];
    acc += xv.x * wv.x + xv.y * wv.y + xv.z * wv.z + xv.w * wv.w;
  }
  float v = acc; int ie = e;
#pragma unroll
  for (int m = 4; m; m >>= 1) {
    float ov = __shfl_xor(v, m, 8);
    int oi = __shfl_xor(ie, m, 8);
    if (ov > v || (ov == v && oi < ie)) { v = ov; ie = oi; }
  }
  if (e == 0) {
    eid[t] = ie;
    rank[t] = atomicAdd(&cnt[ie], 1);
  }
}

// prefix-sum + build dense m-tile table (expert id, row offset within expert)
__global__ void scan_kernel(const int* __restrict__ cnt, int* __restrict__ offs,
                            int* __restrict__ tile_e, int* __restrict__ tile_m,
                            int* __restrict__ ntiles) {
  if (threadIdx.x == 0) {
    int s = 0, nt = 0;
    for (int e = 0; e < NE; ++e) {
      offs[e] = s;
      int c = cnt[e];
      for (int m = 0; m < c; m += 128) { tile_e[nt] = e; tile_m[nt] = m; ++nt; }
      s += c;
    }
    offs[NE] = s;
    *ntiles = nt;
  }
}

// one block per token: write sorted[] and gather x row -> bf16 grouped matrix
__global__ __launch_bounds__(256) void gather_kernel(
    const float* __restrict__ x, const int* __restrict__ eid,
    const int* __restrict__ rank, const int* __restrict__ offs,
    int* __restrict__ sorted, ushort_t* __restrict__ Xg) {
  int t = blockIdx.x;
  int e = eid[t];
  int pos = offs[e] + rank[t];
  if (threadIdx.x == 0) sorted[pos] = t;
  int i = threadIdx.x;  // 256 threads, 4 floats each
  float4 v = ((const float4*)(x + (size_t)t * DIM))[i];
  ushort4 o = make_ushort4(f2b(v.x), f2b(v.y), f2b(v.z), f2b(v.w));
  *(ushort4*)(Xg + (size_t)pos * DIM + i * 4) = o;
}

// ---------------- weight conversion ----------------------------------------
// fc[e][d][h] fp32 -> fct[e][h][d] bf16 (transpose so GEMM1 B is B^T-form)
__global__ __launch_bounds__(256) void transpose_fc_kernel(
    const float* __restrict__ fc, ushort_t* __restrict__ fct) {
  __shared__ float tile[32][33];
  int e = blockIdx.z;
  int h0 = blockIdx.x * 32, d0 = blockIdx.y * 32;
  int c = threadIdx.x & 31, r0 = threadIdx.x >> 5;
  const float* src = fc + ((size_t)e * DIM + d0) * HDIM + h0 + c;
#pragma unroll
  for (int i = 0; i < 4; ++i) {
    int r = r0 + i * 8;
    tile[r][c] = src[(size_t)r * HDIM];
  }
  __syncthreads();
  ushort_t* dst = fct + ((size_t)e * HDIM + h0) * DIM + d0 + c;
#pragma unroll
  for (int i = 0; i < 4; ++i) {
    int r = r0 + i * 8;
    dst[(size_t)r * DIM] = f2b(tile[c][r]);
  }
}

// ---------------- GEMM1: H = relu(Xg @ fct^T)^2, bf16 out -------------------
// C-tile 128x128, 4 waves (2x2), each wave 64x64 = 4x4 of 16x16x32 MFMA
__global__ __launch_bounds__(256, 2) void gemm1_kernel(
    const ushort_t* __restrict__ Xg, const ushort_t* __restrict__ fct,
    const int* __restrict__ offs, const int* __restrict__ tile_e,
    const int* __restrict__ tile_m, const int* __restrict__ ntiles,
    ushort_t* __restrict__ H) {
  if ((int)blockIdx.y >= *ntiles) return;
  int e = tile_e[blockIdx.y];
  int mb = tile_m[blockIdx.y];   // row offset within expert
  int m0 = offs[e];
  int Me = offs[e + 1] - m0;
  int n0 = blockIdx.x * 128;

  __shared__ ushort_t As[128 * 32];
  __shared__ ushort_t Bs[128 * 32];

  int tid = threadIdx.x;
  int wave = tid >> 6;
  int lane = tid & 63;

  const ushort_t* ap[2]; const ushort_t* bp[2];
  ushort_t* al[2]; ushort_t* bl[2];
#pragma unroll
  for (int q = 0; q < 2; ++q) {
    int rl = (wave * 2 + q) * 16 + (lane >> 2);
    int kc = (lane & 3) * 8;
    int rg = mb + rl; if (rg >= Me) rg = Me - 1;  // clamp tail rows
    ap[q] = Xg + (size_t)(m0 + rg) * DIM + kc;
    bp[q] = fct + ((size_t)e * HDIM + n0 + rl) * DIM + kc;
    al[q] = &As[(wave * 2 + q) * 512];
    bl[q] = &Bs[(wave * 2 + q) * 512];
  }

  f32x4 acc[4][4] = {};
  int wm = (wave & 1) * 64;
  int wn = (wave >> 1) * 64;
  int fr = lane & 15;
  int kq = (lane >> 4) * 8;

  for (int k0 = 0; k0 < DIM; k0 += 32) {
    gl2lds16(ap[0] + k0, al[0]);
    gl2lds16(ap[1] + k0, al[1]);
    gl2lds16(bp[0] + k0, bl[0]);
    gl2lds16(bp[1] + k0, bl[1]);
    __syncthreads();  // drains vmcnt(0) then barrier
    bf16x8 af[4], bf[4];
#pragma unroll
    for (int i = 0; i < 4; ++i) {
      af[i] = *(const bf16x8*)&As[(wm + i * 16 + fr) * 32 + kq];
      bf[i] = *(const bf16x8*)&Bs[(wn + i * 16 + fr) * 32 + kq];
    }
#pragma unroll
    for (int i = 0; i < 4; ++i)
#pragma unroll
      for (int j = 0; j < 4; ++j)
        acc[i][j] = __builtin_amdgcn_mfma_f32_16x16x32_bf16(af[i], bf[j], acc[i][j], 0, 0, 0);
    __syncthreads();
  }

  int cq = (lane >> 4) * 4;
#pragma unroll
  for (int i = 0; i < 4; ++i) {
#pragma unroll
    for (int r = 0; r < 4; ++r) {
      int rl = wm + i * 16 + cq + r;
      int rg = mb + rl;
      if (rg < Me) {
        ushort_t* dst = H + (size_t)(m0 + rg) * HDIM + n0 + wn + (lane & 15);
#pragma unroll
        for (int j = 0; j < 4; ++j) {
          float v = acc[i][j][r];
          v = fmaxf(v, 0.f);
          dst[j * 16] = f2b(v * v);
        }
      }
    }
  }
}

// ---------------- GEMM2: P[ks] = H @ proj^T (K-slice), no atomics -----------
// B (proj) staged directly from fp32 input via VGPR->LDS (padded stride 36),
// truncate-packed to bf16 fragments with v_perm. Partials to dense P buffer.
__global__ __launch_bounds__(256, 2) void gemm2_kernel(
    const ushort_t* __restrict__ Hm, const float* __restrict__ pj,
    const int* __restrict__ offs, const int* __restrict__ tile_e,
    const int* __restrict__ tile_m, const int* __restrict__ ntiles,
    float* __restrict__ P) {
  if ((int)blockIdx.y >= *ntiles) return;
  int e = tile_e[blockIdx.y];
  int mb = tile_m[blockIdx.y];
  int ks = blockIdx.z;
  int m0 = offs[e];
  int Me = offs[e + 1] - m0;
  int n0 = blockIdx.x * 128;

  __shared__ ushort_t As[128 * 32];  // bf16 A tile (8 KB)
  __shared__ float Bs[128 * 36];     // fp32 B tile, padded stride 36 (18 KB)

  int tid = threadIdx.x;
  int wave = tid >> 6;
  int lane = tid & 63;

  // A staging: async 16B, 2 chunks/thread
  const ushort_t* ap[2]; ushort_t* al[2];
#pragma unroll
  for (int q = 0; q < 2; ++q) {
    int rl = (wave * 2 + q) * 16 + (lane >> 2);
    int kc = (lane & 3) * 8;
    int rg = mb + rl; if (rg >= Me) rg = Me - 1;
    ap[q] = Hm + (size_t)(m0 + rg) * HDIM + kc;
    al[q] = &As[(wave * 2 + q) * 512];
  }

  // B staging: 4 passes of float4 global load + ds_write (padded LDS)
  const float* bsrc[4]; float* bdst[4];
#pragma unroll
  for (int p = 0; p < 4; ++p) {
    int row = p * 32 + (tid >> 3);  // 0..127
    int ch = tid & 7;               // 4-float chunk within 32-k slice
    bsrc[p] = pj + ((size_t)e * DIM + n0 + row) * HDIM + ch * 4;
    bdst[p] = &Bs[row * 36 + ch * 4];
  }

  f32x4 acc[4][4] = {};
  int wm = (wave & 1) * 64;
  int wn = (wave >> 1) * 64;
  int fr = lane & 15;
  int kq = (lane >> 4) * 8;

  int kbeg = ks * (HDIM / KSPLIT);
  int kend = kbeg + (HDIM / KSPLIT);
  for (int k0 = kbeg; k0 < kend; k0 += 32) {
    gl2lds16(ap[0] + k0, al[0]);
    gl2lds16(ap[1] + k0, al[1]);
    float4 bv[4];
#pragma unroll
    for (int p = 0; p < 4; ++p) bv[p] = *(const float4*)(bsrc[p] + k0);
#pragma unroll
    for (int p = 0; p < 4; ++p) *(float4*)bdst[p] = bv[p];
    __syncthreads();
    bf16x8 af[4], bf[4];
#pragma unroll
    for (int i = 0; i < 4; ++i) {
      af[i] = *(const bf16x8*)&As[(wm + i * 16 + fr) * 32 + kq];
      bf[i] = cvt8(&Bs[(wn + i * 16 + fr) * 36 + kq]);
    }
#pragma unroll
    for (int i = 0; i < 4; ++i)
#pragma unroll
      for (int j = 0; j < 4; ++j)
        acc[i][j] = __builtin_amdgcn_mfma_f32_16x16x32_bf16(af[i], bf[j], acc[i][j], 0, 0, 0);
    __syncthreads();
  }

  int cq = (lane >> 4) * 4;
#pragma unroll
  for (int i = 0; i < 4; ++i) {
#pragma unroll
    for (int r = 0; r < 4; ++r) {
      int rl = wm + i * 16 + cq + r;
      int rg = mb + rl;
      if (rg < Me) {
        float* dst = P + ((size_t)ks * NTOK + (m0 + rg)) * DIM + n0 + wn + (lane & 15);
#pragma unroll
        for (int j = 0; j < 4; ++j) dst[j * 16] = acc[i][j][r];
      }
    }
  }
}

// ---------------- reduce: out[tok] = sum_ks P[ks][pos], coalesced -----------
__global__ __launch_bounds__(256) void reduce_kernel(
    const float* __restrict__ P, const int* __restrict__ sorted,
    float* __restrict__ out) {
  int pos = blockIdx.x;
  int tok = sorted[pos];
  int i = threadIdx.x;
  size_t base = (size_t)pos * DIM + i * 4;
  const size_t S = (size_t)NTOK * DIM;
  f32x4 s = *(const f32x4*)(P + base) + *(const f32x4*)(P + S + base) +
            *(const f32x4*)(P + 2 * S + base) + *(const f32x4*)(P + 3 * S + base);
  *(f32x4*)(out + (size_t)tok * DIM + i * 4) = s;
}

// ---------------- launch -----------------------------------------------------
extern "C" void kernel_launch(void* const* d_in, const int* in_sizes, int n_in,
                              void* d_out, int out_size, void* d_ws, size_t ws_size,
                              hipStream_t stream) {
  const float* x  = (const float*)d_in[0];
  const float* rw = (const float*)d_in[1];
  const float* fc = (const float*)d_in[2];
  const float* pj = (const float*)d_in[3];
  float* out = (float*)d_out;
  char* ws = (char*)d_ws;

  // workspace layout (~106 MiB, same footprint as prior rounds)
  int* eid        = (int*)(ws + 0x0000);       // 16KB
  int* rank       = (int*)(ws + 0x4000);       // 16KB
  int* cnt        = (int*)(ws + 0x8000);       // 32B
  int* offs       = (int*)(ws + 0x8100);       // 36B
  int* tile_e     = (int*)(ws + 0x8200);       // 160B
  int* tile_m     = (int*)(ws + 0x8600);       // 160B
  int* ntiles     = (int*)(ws + 0x8a00);       // 4B
  int* sorted     = (int*)(ws + 0x9000);       // 16KB
  ushort_t* Xg    = (ushort_t*)(ws + 0x10000);    // 8MB  [4096][1024] bf16
  ushort_t* H     = (ushort_t*)(ws + 0x810000);   // 32MB [4096][4096] bf16
  ushort_t* W     = (ushort_t*)(ws + 0x2810000);  // 64MB: fct (gemm1), then P (gemm2 partials)
  float* P        = (float*)W;                    // fct dead after gemm1

  hipMemsetAsync(cnt, 0, 32, stream);
  router_kernel<<<NTOK / 32, 256, 0, stream>>>(x, rw, eid, rank, cnt);
  scan_kernel<<<1, 64, 0, stream>>>(cnt, offs, tile_e, tile_m, ntiles);
  gather_kernel<<<NTOK, 256, 0, stream>>>(x, eid, rank, offs, sorted, Xg);
  transpose_fc_kernel<<<dim3(HDIM / 32, DIM / 32, NE), 256, 0, stream>>>(fc, W);
  gemm1_kernel<<<dim3(HDIM / 128, MAXT), 256, 0, stream>>>(Xg, W, offs, tile_e, tile_m, ntiles, H);
  gemm2_kernel<<<dim3(DIM / 128, MAXT, KSPLIT), 256, 0, stream>>>(H, pj, offs, tile_e, tile_m, ntiles, P);
  reduce_kernel<<<NTOK, 256, 0, stream>>>(P, sorted, out);
}